// Round 6
// baseline (422.667 us; speedup 1.0000x reference)
//
#include <hip/hip_runtime.h>
#include <math.h>

#define BATCH 2048
#define DIN   784
#define HID   512
#define NC    10
#define NS    10

constexpr int HP  = HID + 1;        // 513
constexpr int M2  = NS * BATCH;     // 20480
constexpr int KP2 = 544;            // 513 padded to 17*32
constexpr int KP1 = 800;            // 784 padded to 25*32
constexpr int HROW = 544;           // padded h row length (bf16)

typedef __attribute__((ext_vector_type(8))) short          short8;
typedef __attribute__((ext_vector_type(8))) unsigned short ushort8;
typedef __attribute__((ext_vector_type(4))) float          floatx4;

__device__ inline unsigned short f2bf(float f) {
    unsigned u = __builtin_bit_cast(unsigned, f);
    u += 0x7FFFu + ((u >> 16) & 1u);
    return (unsigned short)(u >> 16);
}
__device__ inline float bf2f(unsigned short u) {
    return __builtin_bit_cast(float, (unsigned)u << 16);
}

// square each of 8 bf16 lanes; repack via v_perm_b32
__device__ inline short8 sq8(short8 a) {
    union { short8 s; unsigned u[4]; } x;
    x.s = a;
#pragma unroll
    for (int i = 0; i < 4; ++i) {
        unsigned t = x.u[i];
        float lo = __builtin_bit_cast(float, t << 16);
        float hi = __builtin_bit_cast(float, t & 0xFFFF0000u);
        unsigned lq = __builtin_bit_cast(unsigned, lo * lo);
        unsigned hq = __builtin_bit_cast(unsigned, hi * hi);
        x.u[i] = __builtin_amdgcn_perm(hq, lq, 0x07060302u);
    }
    return x.s;
}

// ---------------------------------------------------------------------------
// Barrier-free dual MFMA GEMM: accm = A@Wm, accs = (A.*A)@Ws2.
// No LDS. Each wave computes 32 rows x 32 cols; fragments loaded directly
// global->VGPR (B panel is L2-hot: 32 cols x Kp x 2 mats = ~70-100 KB shared
// by 640 waves; A rows shared by the 16 co-resident blockIdx.x siblings).
// KT is a compile-time ktile count -> full unroll, offsets in load immediates,
// compiler pipelines with fine-grained vmcnt (no vmcnt(0) barrier drain).
// Block = 256 thr = 4 waves stacked in M: block tile 128(M) x 32(N).
// ---------------------------------------------------------------------------
template<int KT, bool FUSED>
__global__ __launch_bounds__(256)
void dual_gemm_nolds(const unsigned short* __restrict__ A,
                     const unsigned short* __restrict__ WTm,
                     const unsigned short* __restrict__ WTs2,
                     const float* __restrict__ eps,
                     unsigned short* __restrict__ hout,
                     float* __restrict__ mu_out,
                     float* __restrict__ sg_out)
{
    constexpr int Kp = KT * 32;
    const int tid  = threadIdx.x;
    const int lane = tid & 63;
    const int w    = tid >> 6;
    const int quad = lane >> 4;
    const int l16  = lane & 15;

    const int row0 = blockIdx.y * 128 + w * 32;   // this wave's 32-row slice
    const int col0 = blockIdx.x * 32;

    // lane fragment base pointers (k-offset quad*8 elements)
    const unsigned short* gA0  = A + (size_t)(row0 + l16) * Kp + quad * 8;
    const unsigned short* gA1  = gA0 + (size_t)16 * Kp;
    const unsigned short* gBm0 = WTm  + (size_t)(col0 + l16) * Kp + quad * 8;
    const unsigned short* gBm1 = gBm0 + (size_t)16 * Kp;
    const unsigned short* gBs0 = WTs2 + (size_t)(col0 + l16) * Kp + quad * 8;
    const unsigned short* gBs1 = gBs0 + (size_t)16 * Kp;

    floatx4 accm[2][2] = {};
    floatx4 accs[2][2] = {};

#pragma unroll
    for (int kt = 0; kt < KT; ++kt) {
        const int ko = kt * 32;
        const short8 a0  = *(const short8*)(gA0  + ko);
        const short8 a1  = *(const short8*)(gA1  + ko);
        const short8 bm0 = *(const short8*)(gBm0 + ko);
        const short8 bm1 = *(const short8*)(gBm1 + ko);
        const short8 bs0 = *(const short8*)(gBs0 + ko);
        const short8 bs1 = *(const short8*)(gBs1 + ko);
        const short8 q0 = sq8(a0);
        const short8 q1 = sq8(a1);
        accm[0][0] = __builtin_amdgcn_mfma_f32_16x16x32_bf16(a0, bm0, accm[0][0], 0, 0, 0);
        accm[0][1] = __builtin_amdgcn_mfma_f32_16x16x32_bf16(a0, bm1, accm[0][1], 0, 0, 0);
        accm[1][0] = __builtin_amdgcn_mfma_f32_16x16x32_bf16(a1, bm0, accm[1][0], 0, 0, 0);
        accm[1][1] = __builtin_amdgcn_mfma_f32_16x16x32_bf16(a1, bm1, accm[1][1], 0, 0, 0);
        accs[0][0] = __builtin_amdgcn_mfma_f32_16x16x32_bf16(q0, bs0, accs[0][0], 0, 0, 0);
        accs[0][1] = __builtin_amdgcn_mfma_f32_16x16x32_bf16(q0, bs1, accs[0][1], 0, 0, 0);
        accs[1][0] = __builtin_amdgcn_mfma_f32_16x16x32_bf16(q1, bs0, accs[1][0], 0, 0, 0);
        accs[1][1] = __builtin_amdgcn_mfma_f32_16x16x32_bf16(q1, bs1, accs[1][1], 0, 0, 0);
    }

    // epilogue: C/D layout col=lane&15, row=quad*4+reg
    if (FUSED) {
#pragma unroll
        for (int rg = 0; rg < 2; ++rg)
#pragma unroll
            for (int j = 0; j < 2; ++j)
#pragma unroll
                for (int r = 0; r < 4; ++r) {
                    const int R = row0 + rg * 16 + quad * 4 + r;
                    const int C = col0 + j * 16 + l16;
                    const float sg = sqrtf(accs[rg][j][r] + 1e-12f);
                    float v = accm[rg][j][r] + sg * eps[(size_t)R * HID + C];
                    v = v > 0.0f ? v : 0.01f * v;
                    hout[(size_t)R * HROW + C] = f2bf(v);
                }
    } else {
#pragma unroll
        for (int rg = 0; rg < 2; ++rg)
#pragma unroll
            for (int j = 0; j < 2; ++j)
#pragma unroll
                for (int r = 0; r < 4; ++r) {
                    const int R = row0 + rg * 16 + quad * 4 + r;
                    const int C = col0 + j * 16 + l16;
                    const size_t o = (size_t)R * HID + C;
                    mu_out[o] = accm[rg][j][r];
                    sg_out[o] = sqrtf(accs[rg][j][r] + 1e-12f);
                }
    }
}

// ---------------------------------------------------------------------------
// Weight pack: WTm[n][k] = bf16(Wm[k][n]); WTs2[n][k] = bf16((drop*Ws[k][n])^2)
// ---------------------------------------------------------------------------
__global__ __launch_bounds__(256)
void pack_wT(const float* __restrict__ Wm, const float* __restrict__ Ws,
             const float* __restrict__ dropPtr, int K, int Kp,
             unsigned short* __restrict__ WTm, unsigned short* __restrict__ WTs2)
{
    __shared__ float tm[32][33];
    __shared__ float ts[32][33];
    const float drop = dropPtr[0];
    const int k0 = blockIdx.x * 32, n0 = blockIdx.y * 32;
    const int tx = threadIdx.x, ty = threadIdx.y;   // 32 x 8
#pragma unroll
    for (int i = 0; i < 4; ++i) {
        const int k = k0 + ty + 8 * i;
        float m = 0.0f, s2 = 0.0f;
        if (k < K) {
            m = Wm[(size_t)k * HID + n0 + tx];
            const float s = Ws[(size_t)k * HID + n0 + tx] * drop;
            s2 = s * s;
        }
        tm[ty + 8 * i][tx] = m;
        ts[ty + 8 * i][tx] = s2;
    }
    __syncthreads();
#pragma unroll
    for (int i = 0; i < 4; ++i) {
        const int n = n0 + ty + 8 * i;
        WTm[(size_t)n * Kp + k0 + tx]  = f2bf(tm[tx][ty + 8 * i]);
        WTs2[(size_t)n * Kp + k0 + tx] = f2bf(ts[tx][ty + 8 * i]);
    }
}

// convert inputs f32 [2048 x 784] -> bf16 [2048 x 800] zero-padded
__global__ __launch_bounds__(256)
void convert_x(const float* __restrict__ x, unsigned short* __restrict__ xb)
{
    const int idx = blockIdx.x * 256 + threadIdx.x;   // 2048*100
    if (idx >= BATCH * 100) return;
    const int r = idx / 100;
    const int c8 = (idx - r * 100) * 8;
    ushort8 o;
    if (c8 < DIN) {   // DIN=784=98*8
        const floatx4 a = *(const floatx4*)(x + (size_t)r * DIN + c8);
        const floatx4 b = *(const floatx4*)(x + (size_t)r * DIN + c8 + 4);
#pragma unroll
        for (int j = 0; j < 4; ++j) { o[j] = f2bf(a[j]); o[4 + j] = f2bf(b[j]); }
    } else {
#pragma unroll
        for (int j = 0; j < 8; ++j) o[j] = 0;
    }
    *(ushort8*)(xb + (size_t)r * KP1 + c8) = o;
}

// h1[r][c] = bf16(leaky(mu1[b][c] + sg1[b][c]*eps1[r][c])), full 544-row incl pad
__global__ __launch_bounds__(256)
void expand1(const float* __restrict__ mu1, const float* __restrict__ sg1,
             const float* __restrict__ eps1, unsigned short* __restrict__ h1)
{
    const int idx = blockIdx.x * 256 + threadIdx.x;   // M2*68
    if (idx >= M2 * 68) return;
    const int r  = idx / 68;
    const int c8 = (idx - r * 68) * 8;
    ushort8 o;
    if (c8 < HID) {
        const int b = r & (BATCH - 1);
        const floatx4* ep = (const floatx4*)(eps1 + (size_t)r * HID + c8);
        const floatx4* mp = (const floatx4*)(mu1 + (size_t)b * HID + c8);
        const floatx4* sp = (const floatx4*)(sg1 + (size_t)b * HID + c8);
        const floatx4 e0 = ep[0], e1 = ep[1];
        const floatx4 m0 = mp[0], m1 = mp[1];
        const floatx4 s0 = sp[0], s1 = sp[1];
#pragma unroll
        for (int j = 0; j < 4; ++j) {
            float v = m0[j] + s0[j] * e0[j];
            v = v > 0.0f ? v : 0.01f * v;
            o[j] = f2bf(v);
            float u = m1[j] + s1[j] * e1[j];
            u = u > 0.0f ? u : 0.01f * u;
            o[4 + j] = f2bf(u);
        }
    } else {
#pragma unroll
        for (int j = 0; j < 8; ++j) o[j] = 0;
        if (c8 == HID) o[0] = 0x3F80;   // bf16(1.0) ones column
    }
    *(ushort8*)(h1 + (size_t)r * HROW + c8) = o;
}

// pad columns 512..543 of an h buffer (ones col + zeros)
__global__ __launch_bounds__(256)
void pad_h(unsigned short* __restrict__ h)
{
    const int idx = blockIdx.x * 256 + threadIdx.x;   // M2*4
    if (idx >= M2 * 4) return;
    const int r = idx >> 2, seg = idx & 3;
    ushort8 o;
#pragma unroll
    for (int j = 0; j < 8; ++j) o[j] = 0;
    if (seg == 0) o[0] = 0x3F80;
    *(ushort8*)(h + (size_t)r * HROW + HID + seg * 8) = o;
}

// Layer 4: per-wave dot products (N=10) + fused log_softmax; h3 is bf16 [M2 x 544]
__global__ __launch_bounds__(256)
void layer4(const unsigned short* __restrict__ h3, const float* __restrict__ Wm,
            const float* __restrict__ Ws, const float* __restrict__ eps4,
            float* __restrict__ out)
{
    const int wave = (int)((blockIdx.x * 256 + threadIdx.x) >> 6);
    const int lane = threadIdx.x & 63;
    if (wave >= M2) return;

    const unsigned short* x = h3 + (size_t)wave * HROW;
    float am[NC] = {}, as[NC] = {};
    for (int k = lane; k < HP; k += 64) {
        const float xv = bf2f(x[k]);
        const float xs = xv * xv;
#pragma unroll
        for (int c = 0; c < NC; ++c) {
            am[c] = fmaf(xv, Wm[k * NC + c], am[c]);
            const float s = Ws[k * NC + c];
            as[c] = fmaf(xs, s * s, as[c]);
        }
    }
#pragma unroll
    for (int off = 32; off; off >>= 1) {
#pragma unroll
        for (int c = 0; c < NC; ++c) {
            am[c] += __shfl_xor(am[c], off, 64);
            as[c] += __shfl_xor(as[c], off, 64);
        }
    }
    if (lane == 0) {
        float logit[NC];
        float mx = -1e30f;
#pragma unroll
        for (int c = 0; c < NC; ++c) {
            const float sg = sqrtf(as[c] + 1e-12f);
            logit[c] = am[c] + sg * eps4[(size_t)wave * NC + c];
            mx = fmaxf(mx, logit[c]);
        }
        float sum = 0.0f;
#pragma unroll
        for (int c = 0; c < NC; ++c) sum += expf(logit[c] - mx);
        const float lse = mx + logf(sum);
#pragma unroll
        for (int c = 0; c < NC; ++c) out[(size_t)wave * NC + c] = logit[c] - lse;
    }
}

// ---------------------------------------------------------------------------
extern "C" void kernel_launch(void* const* d_in, const int* in_sizes, int n_in,
                              void* d_out, int out_size, void* d_ws, size_t ws_size,
                              hipStream_t stream)
{
    const float* inputs   = (const float*)d_in[0];
    const float* a1_mean  = (const float*)d_in[1];
    const float* a1_scale = (const float*)d_in[2];
    const float* a1_drop  = (const float*)d_in[3];
    const float* a2_mean  = (const float*)d_in[4];
    const float* a2_scale = (const float*)d_in[5];
    const float* a2_drop  = (const float*)d_in[6];
    const float* a3_mean  = (const float*)d_in[7];
    const float* a3_scale = (const float*)d_in[8];
    const float* a3_drop  = (const float*)d_in[9];
    const float* a4_mean  = (const float*)d_in[10];
    const float* a4_scale = (const float*)d_in[11];
    const float* eps1     = (const float*)d_in[12];
    const float* eps2     = (const float*)d_in[13];
    const float* eps3     = (const float*)d_in[14];
    const float* eps4     = (const float*)d_in[15];
    float* out = (float*)d_out;

    char* p = (char*)d_ws;
    unsigned short* h_a  = (unsigned short*)p; p += (size_t)M2 * HROW * 2;
    unsigned short* h_b  = (unsigned short*)p; p += (size_t)M2 * HROW * 2;
    unsigned short* xb   = (unsigned short*)p; p += (size_t)BATCH * KP1 * 2;
    unsigned short* WT1m = (unsigned short*)p; p += (size_t)HID * KP1 * 2;
    unsigned short* WT1s = (unsigned short*)p; p += (size_t)HID * KP1 * 2;
    unsigned short* WT2m = (unsigned short*)p; p += (size_t)HID * KP2 * 2;
    unsigned short* WT2s = (unsigned short*)p; p += (size_t)HID * KP2 * 2;
    unsigned short* WT3m = (unsigned short*)p; p += (size_t)HID * KP2 * 2;
    unsigned short* WT3s = (unsigned short*)p; p += (size_t)HID * KP2 * 2;
    float* mu1 = (float*)p; p += (size_t)BATCH * HID * 4;
    float* sg1 = (float*)p; p += (size_t)BATCH * HID * 4;

    // pack / convert
    convert_x<<<(BATCH * 100 + 255) / 256, 256, 0, stream>>>(inputs, xb);
    pack_wT<<<dim3(KP1 / 32, HID / 32), dim3(32, 8), 0, stream>>>(a1_mean, a1_scale, a1_drop, DIN, KP1, WT1m, WT1s);
    pack_wT<<<dim3(KP2 / 32, HID / 32), dim3(32, 8), 0, stream>>>(a2_mean, a2_scale, a2_drop, HP, KP2, WT2m, WT2s);
    pack_wT<<<dim3(KP2 / 32, HID / 32), dim3(32, 8), 0, stream>>>(a3_mean, a3_scale, a3_drop, HP, KP2, WT3m, WT3s);
    pad_h<<<(M2 * 4 + 255) / 256, 256, 0, stream>>>(h_b);

    // layer 1 (sample-shared): mu1/sg1 [2048 x 512]
    dual_gemm_nolds<KP1 / 32, false><<<dim3(HID / 32, BATCH / 128), 256, 0, stream>>>(
        xb, WT1m, WT1s, nullptr, nullptr, mu1, sg1);

    // expand to h1 [20480 x 544] (incl ones + zero pad)
    expand1<<<(M2 * 68 + 255) / 256, 256, 0, stream>>>(mu1, sg1, eps1, h_a);

    // layer 2 fused -> h_b
    dual_gemm_nolds<KP2 / 32, true><<<dim3(HID / 32, M2 / 128), 256, 0, stream>>>(
        h_a, WT2m, WT2s, eps2, h_b, nullptr, nullptr);

    // layer 3 fused -> h_a (pad cols survive from expand1)
    dual_gemm_nolds<KP2 / 32, true><<<dim3(HID / 32, M2 / 128), 256, 0, stream>>>(
        h_b, WT3m, WT3s, eps3, h_a, nullptr, nullptr);

    // layer 4 + log_softmax
    layer4<<<(M2 * 64 + 255) / 256, 256, 0, stream>>>(h_a, a4_mean, a4_scale, eps4, out);
}